// Round 1
// baseline (449.576 us; speedup 1.0000x reference)
//
#include <hip/hip_runtime.h>

typedef __attribute__((ext_vector_type(8))) short short8;
typedef __attribute__((ext_vector_type(4))) float f32x4;

#define LDSW 136  // LDS row stride in shorts: 128 + 8 pad -> 2-way bank aliasing (free)

static __device__ __forceinline__ unsigned short f2bf(float f) {
    union { float f; unsigned int u; } v; v.f = f;
    unsigned int r = v.u + 0x7fffu + ((v.u >> 16) & 1u);  // RNE
    return (unsigned short)(r >> 16);
}

static __device__ __forceinline__ short8 cvt8(const float* __restrict__ src) {
    float4 f0 = *(const float4*)src;
    float4 f1 = *(const float4*)(src + 4);
    short8 a;
    a[0] = (short)f2bf(f0.x); a[1] = (short)f2bf(f0.y);
    a[2] = (short)f2bf(f0.z); a[3] = (short)f2bf(f0.w);
    a[4] = (short)f2bf(f1.x); a[5] = (short)f2bf(f1.y);
    a[6] = (short)f2bf(f1.z); a[7] = (short)f2bf(f1.w);
    return a;
}

// load one 128x128 bf16 matrix from global into padded LDS (256 threads)
static __device__ __forceinline__ void load_w_lds(unsigned short* lds,
                                                  const unsigned short* __restrict__ Wg,
                                                  int tid) {
    const uint4* src = (const uint4*)Wg;
#pragma unroll
    for (int it = 0; it < 8; ++it) {
        int idx = tid + it * 256;       // 2048 chunks of 8 shorts
        int row = idx >> 4;
        int col = (idx & 15) << 3;
        *(uint4*)&lds[row * LDSW + col] = src[idx];
    }
}

__global__ void k_zero(uint4* p, int n16) {
    int i = blockIdx.x * blockDim.x + threadIdx.x;
    if (i < n16) p[i] = uint4{0u, 0u, 0u, 0u};
}

// convert W1,W2 (f32 [128][256]) into 4 bf16 [128][128] matrices (row j = output col)
__global__ void k_convw(const float* __restrict__ W1, const float* __restrict__ W2,
                        unsigned short* W1a, unsigned short* W1b,
                        unsigned short* W2a, unsigned short* W2b) {
    int j = blockIdx.x;
    int k = threadIdx.x;
    float w1 = W1[j * 256 + k], w2 = W2[j * 256 + k];
    if (k < 128) { W1a[j * 128 + k] = f2bf(w1); W2a[j * 128 + k] = f2bf(w2); }
    else         { W1b[j * 128 + k - 128] = f2bf(w1); W2b[j * 128 + k - 128] = f2bf(w2); }
}

__global__ void k_mark(const int* __restrict__ ids, int* __restrict__ cum, int n) {
    int i = blockIdx.x * blockDim.x + threadIdx.x;
    if (i < n) cum[ids[i]] = 1;
}

// single-block inclusive scan over cum[0..G)
__global__ __launch_bounds__(1024) void k_scan(int* __restrict__ cum, int G) {
    int tid = threadIdx.x;
    int ELT = (G + 1023) >> 10;
    int base = tid * ELT;
    int s = 0;
    for (int j = 0; j < ELT; ++j) { int idx = base + j; if (idx < G) s += cum[idx]; }
    int lane = tid & 63, wv = tid >> 6;
    int v = s;
#pragma unroll
    for (int off = 1; off < 64; off <<= 1) {
        int u = __shfl_up(v, off, 64);
        if (lane >= off) v += u;
    }
    __shared__ int wsum[16];
    if (lane == 63) wsum[wv] = v;
    __syncthreads();
    if (tid == 0) {
        int accu = 0;
        for (int w = 0; w < 16; ++w) { int t = wsum[w]; wsum[w] = accu; accu += t; }
    }
    __syncthreads();
    int run = wsum[wv] + (v - s);  // exclusive prefix for this thread
    for (int j = 0; j < ELT; ++j) {
        int idx = base + j;
        if (idx < G) { run += cum[idx]; cum[idx] = run; }
    }
}

__global__ void k_gid(const int* __restrict__ ids, const int* __restrict__ cum,
                      int* __restrict__ gid, int* __restrict__ gstart,
                      int* __restrict__ ngr, int n) {
    int i = blockIdx.x * blockDim.x + threadIdx.x;
    if (i >= n) return;
    int v = ids[i];
    int g = cum[v] - 1;
    gid[i] = g;
    if (i == 0 || ids[i - 1] != v) gstart[g] = i;
    if (i == n - 1) { gstart[g + 1] = n; *ngr = g + 1; }
}

// E1 = emb @ W1b^T  (f32 out, bf16 MFMA), rows = G
__global__ __launch_bounds__(256) void k_egemm(const float* __restrict__ emb,
                                               const unsigned short* __restrict__ Wg,
                                               float* __restrict__ E1, int G) {
    __shared__ unsigned short lds[128 * LDSW];
    int tid = threadIdx.x;
    load_w_lds(lds, Wg, tid);
    __syncthreads();
    int lane = tid & 63, wid = tid >> 6;
    int p = lane & 15, q = lane >> 4;
    int R = blockIdx.x * 64 + wid * 16;

    short8 a[4];
#pragma unroll
    for (int kk = 0; kk < 4; ++kk) {
        int r = R + p;
        short8 av = {0, 0, 0, 0, 0, 0, 0, 0};
        if (r < G) av = cvt8(emb + (size_t)r * 128 + kk * 32 + q * 8);
        a[kk] = av;
    }
    f32x4 acc[8];
#pragma unroll
    for (int t = 0; t < 8; ++t) acc[t] = f32x4{0.f, 0.f, 0.f, 0.f};
#pragma unroll
    for (int t = 0; t < 8; ++t)
#pragma unroll
        for (int kk = 0; kk < 4; ++kk) {
            short8 b = *(const short8*)&lds[(t * 16 + p) * LDSW + kk * 32 + q * 8];
            acc[t] = __builtin_amdgcn_mfma_f32_16x16x32_bf16(a[kk], b, acc[t], 0, 0, 0);
        }
#pragma unroll
    for (int t = 0; t < 8; ++t) {
        int col = t * 16 + p;
#pragma unroll
        for (int rg = 0; rg < 4; ++rg) {
            int r = R + q * 4 + rg;
            if (r < G) E1[(size_t)r * 128 + col] = acc[t][rg];
        }
    }
}

// x_out = x @ W1a^T + E1[gid] + b1 ; fused per-block segment partial sums into segsum
__global__ __launch_bounds__(256) void k_xgemm(const float* __restrict__ x,
                                               const unsigned short* __restrict__ Wg,
                                               const int* __restrict__ gid,
                                               const float* __restrict__ E1,
                                               const float* __restrict__ b1,
                                               float* __restrict__ out,
                                               float* __restrict__ segsum, int N) {
    __shared__ unsigned short lds[128 * LDSW];
    int tid = threadIdx.x;
    load_w_lds(lds, Wg, tid);
    __syncthreads();
    int lane = tid & 63, wid = tid >> 6;
    int p = lane & 15, q = lane >> 4;
    int R = blockIdx.x * 64 + wid * 16;

    short8 a[4];
#pragma unroll
    for (int kk = 0; kk < 4; ++kk) {
        int r = R + p;
        short8 av = {0, 0, 0, 0, 0, 0, 0, 0};
        if (r < N) av = cvt8(x + (size_t)r * 128 + kk * 32 + q * 8);
        a[kk] = av;
    }
    f32x4 acc[8];
#pragma unroll
    for (int t = 0; t < 8; ++t) acc[t] = f32x4{0.f, 0.f, 0.f, 0.f};
#pragma unroll
    for (int t = 0; t < 8; ++t)
#pragma unroll
        for (int kk = 0; kk < 4; ++kk) {
            short8 b = *(const short8*)&lds[(t * 16 + p) * LDSW + kk * 32 + q * 8];
            acc[t] = __builtin_amdgcn_mfma_f32_16x16x32_bf16(a[kk], b, acc[t], 0, 0, 0);
        }
    int g4[4];
#pragma unroll
    for (int rg = 0; rg < 4; ++rg) {
        int r = R + q * 4 + rg;
        g4[rg] = (r < N) ? gid[r] : 0;
    }
    float bv[8];
#pragma unroll
    for (int t = 0; t < 8; ++t) bv[t] = b1[t * 16 + p];
#pragma unroll
    for (int t = 0; t < 8; ++t) {
        int col = t * 16 + p;
#pragma unroll
        for (int rg = 0; rg < 4; ++rg) {
            int r = R + q * 4 + rg;
            if (r < N)
                out[(size_t)r * 128 + col] = acc[t][rg] + E1[(size_t)g4[rg] * 128 + col] + bv[t];
        }
    }
    // fused segment partial sums (x re-read is L1/L2-hot; rows of a group contiguous)
    int col = tid & 127, half = tid >> 7;
    int rbeg = blockIdx.x * 64 + half * 32;
    int rend = min(rbeg + 32, N);
    if (rbeg < rend) {
        int gprev = gid[rbeg];
        float fs = 0.f;
        for (int r = rbeg; r < rend; ++r) {
            int g = gid[r];
            if (g != gprev) { atomicAdd(&segsum[(size_t)gprev * 128 + col], fs); fs = 0.f; gprev = g; }
            fs += x[(size_t)r * 128 + col];
        }
        atomicAdd(&segsum[(size_t)gprev * 128 + col], fs);
    }
}

// imp_second (bf16) from segment sums / counts, else emb
__global__ void k_mean(const float* __restrict__ segsum, const float* __restrict__ emb,
                       const int* __restrict__ gstart, const int* __restrict__ ngr,
                       unsigned short* __restrict__ imps, int G) {
    int i = blockIdx.x * blockDim.x + threadIdx.x;  // one per 4 elements
    if (i * 4 >= G * 128) return;
    int g = (i * 4) >> 7;
    int ng = *ngr;
    float4 v;
    if (g < ng - 1) {
        int cnt = gstart[g + 1] - gstart[g];
        float inv = 1.0f / (float)max(cnt, 1);
        v = ((const float4*)segsum)[i];
        v.x *= inv; v.y *= inv; v.z *= inv; v.w *= inv;
    } else {
        v = ((const float4*)emb)[i];
    }
    unsigned int lo = (unsigned int)f2bf(v.x) | ((unsigned int)f2bf(v.y) << 16);
    unsigned int hi = (unsigned int)f2bf(v.z) | ((unsigned int)f2bf(v.w) << 16);
    ((uint2*)imps)[i] = uint2{lo, hi};
}

// imputed_out = emb @ W2a^T + imps @ W2b^T + b2
__global__ __launch_bounds__(256) void k_igemm(const float* __restrict__ emb,
                                               const unsigned short* __restrict__ imps,
                                               const unsigned short* __restrict__ W2ag,
                                               const unsigned short* __restrict__ W2bg,
                                               const float* __restrict__ b2,
                                               float* __restrict__ out2, int G) {
    __shared__ unsigned short lds[2 * 128 * LDSW];
    int tid = threadIdx.x;
    load_w_lds(lds, W2ag, tid);
    load_w_lds(lds + 128 * LDSW, W2bg, tid);
    __syncthreads();
    int lane = tid & 63, wid = tid >> 6;
    int p = lane & 15, q = lane >> 4;
    int R = blockIdx.x * 64 + wid * 16;

    short8 ea[4], ia[4];
#pragma unroll
    for (int kk = 0; kk < 4; ++kk) {
        int r = R + p;
        short8 z = {0, 0, 0, 0, 0, 0, 0, 0};
        ea[kk] = z; ia[kk] = z;
        if (r < G) {
            ea[kk] = cvt8(emb + (size_t)r * 128 + kk * 32 + q * 8);
            ia[kk] = *(const short8*)&imps[(size_t)r * 128 + kk * 32 + q * 8];
        }
    }
    f32x4 acc[8];
#pragma unroll
    for (int t = 0; t < 8; ++t) acc[t] = f32x4{0.f, 0.f, 0.f, 0.f};
#pragma unroll
    for (int t = 0; t < 8; ++t) {
#pragma unroll
        for (int kk = 0; kk < 4; ++kk) {
            short8 b = *(const short8*)&lds[(t * 16 + p) * LDSW + kk * 32 + q * 8];
            acc[t] = __builtin_amdgcn_mfma_f32_16x16x32_bf16(ea[kk], b, acc[t], 0, 0, 0);
        }
#pragma unroll
        for (int kk = 0; kk < 4; ++kk) {
            short8 b = *(const short8*)&lds[128 * LDSW + (t * 16 + p) * LDSW + kk * 32 + q * 8];
            acc[t] = __builtin_amdgcn_mfma_f32_16x16x32_bf16(ia[kk], b, acc[t], 0, 0, 0);
        }
    }
#pragma unroll
    for (int t = 0; t < 8; ++t) {
        int col = t * 16 + p;
        float bb = b2[col];
#pragma unroll
        for (int rg = 0; rg < 4; ++rg) {
            int r = R + q * 4 + rg;
            if (r < G) out2[(size_t)r * 128 + col] = acc[t][rg] + bb;
        }
    }
}

extern "C" void kernel_launch(void* const* d_in, const int* in_sizes, int n_in,
                              void* d_out, int out_size, void* d_ws, size_t ws_size,
                              hipStream_t stream) {
    const float* x   = (const float*)d_in[0];
    const float* emb = (const float*)d_in[1];
    const float* W1  = (const float*)d_in[2];
    const float* b1  = (const float*)d_in[3];
    const float* W2  = (const float*)d_in[4];
    const float* b2  = (const float*)d_in[5];
    const int*   ids = (const int*)d_in[6];
    const int H = 128;
    const int N = in_sizes[6];
    const int G = in_sizes[1] / H;

    float* out  = (float*)d_out;
    float* out2 = out + (size_t)N * H;
    float* E1   = out2;  // reuse imputed_out region as E1 scratch (overwritten by k_igemm last)

    char* ws = (char*)d_ws;
    size_t off = 0;
    float* segsum = (float*)(ws + off); off += (size_t)G * H * 4;
    int*   cum    = (int*)(ws + off);   off += (size_t)G * 4;
    size_t zbytes = off;                              // contiguous zero region: segsum + cum
    off = (off + 255) & ~(size_t)255;
    int* gid    = (int*)(ws + off); off += (size_t)N * 4;       off = (off + 255) & ~(size_t)255;
    int* gstart = (int*)(ws + off); off += (size_t)(G + 1) * 4; off = (off + 255) & ~(size_t)255;
    int* ngr    = (int*)(ws + off); off += 256;
    unsigned short* W1a = (unsigned short*)(ws + off); off += (size_t)H * H * 2;
    unsigned short* W1b = (unsigned short*)(ws + off); off += (size_t)H * H * 2;
    unsigned short* W2a = (unsigned short*)(ws + off); off += (size_t)H * H * 2;
    unsigned short* W2b = (unsigned short*)(ws + off); off += (size_t)H * H * 2;
    unsigned short* imps = (unsigned short*)(ws + off); off += (size_t)G * H * 2;

    int n16 = (int)(zbytes / 16);
    k_zero<<<(n16 + 255) / 256, 256, 0, stream>>>((uint4*)ws, n16);
    k_convw<<<H, 256, 0, stream>>>(W1, W2, W1a, W1b, W2a, W2b);
    k_mark<<<(N + 255) / 256, 256, 0, stream>>>(ids, cum, N);
    k_scan<<<1, 1024, 0, stream>>>(cum, G);
    k_gid<<<(N + 255) / 256, 256, 0, stream>>>(ids, cum, gid, gstart, ngr, N);
    k_egemm<<<(G + 63) / 64, 256, 0, stream>>>(emb, W1b, E1, G);
    k_xgemm<<<(N + 63) / 64, 256, 0, stream>>>(x, W1a, gid, E1, b1, out, segsum, N);
    k_mean<<<(G * H / 4 + 255) / 256, 256, 0, stream>>>(segsum, emb, gstart, ngr, imps, G);
    k_igemm<<<(G + 63) / 64, 256, 0, stream>>>(emb, imps, W2a, W2b, b2, out2, G);
}

// Round 2
// 432.215 us; speedup vs baseline: 1.0402x; 1.0402x over previous
//
#include <hip/hip_runtime.h>

typedef __attribute__((ext_vector_type(8))) short short8;
typedef __attribute__((ext_vector_type(4))) float f32x4;
typedef unsigned long long ull;

static __device__ __forceinline__ unsigned short f2bf(float f) {
    union { float f; unsigned int u; } v; v.f = f;
    unsigned int r = v.u + 0x7fffu + ((v.u >> 16) & 1u);  // RNE
    return (unsigned short)(r >> 16);
}

static __device__ __forceinline__ void dma16(const void* g, void* l) {
    __builtin_amdgcn_global_load_lds(
        (const __attribute__((address_space(1))) unsigned int*)g,
        (__attribute__((address_space(3))) unsigned int*)l, 16, 0, 0);
}

// DMA one 32-row f32 chunk (16KB) into LDS with row-XOR swizzle.
// LDS stays linear (global_load_lds requirement); source address pre-swizzled.
// Layout: logical byte L = r*512 + c*4 stored at L ^ ((r&7)<<4).
static __device__ __forceinline__ void dma_chunk(const float* __restrict__ src,
                                                 char* ldsbase, long long grow0,
                                                 long long nrows, int wid, int lane) {
#pragma unroll
    for (int k = 0; k < 4; ++k) {
        int doff = wid * 4096 + k * 1024 + lane * 16;   // dest byte offset in chunk
        int r = doff >> 9;                               // logical row of this 16B
        long long srcb = (grow0 + r) * 512 + (long long)((doff & 511) ^ ((r & 7) << 4));
        long long maxb = nrows * 512 - 16;
        srcb = srcb < maxb ? srcb : maxb;                // clamp OOB rows (garbage ok)
        dma16((const char*)src + srcb, ldsbase + wid * 4096 + k * 1024);
    }
}

static __device__ __forceinline__ float4 lds_rd16(const float* buf, int boff, int sw) {
    return *(const float4*)((const char*)buf + (boff ^ sw));
}

__global__ void k_zero(uint4* p, int n16) {
    int i = blockIdx.x * blockDim.x + threadIdx.x;
    if (i < n16) p[i] = uint4{0u, 0u, 0u, 0u};
}

// W1,W2 (f32 [128][256]) -> 4 bf16 [128][128] row-major (row j = output col j)
__global__ void k_convw(const float* __restrict__ W1, const float* __restrict__ W2,
                        unsigned short* W1a, unsigned short* W1b,
                        unsigned short* W2a, unsigned short* W2b) {
    int j = blockIdx.x;
    int k = threadIdx.x;
    float w1 = W1[j * 256 + k], w2 = W2[j * 256 + k];
    if (k < 128) { W1a[j * 128 + k] = f2bf(w1); W2a[j * 128 + k] = f2bf(w2); }
    else         { W1b[j * 128 + k - 128] = f2bf(w1); W2b[j * 128 + k - 128] = f2bf(w2); }
}

__global__ void k_mark(const int* __restrict__ ids, int* __restrict__ cum, int n) {
    int i = blockIdx.x * blockDim.x + threadIdx.x;
    if (i < n) cum[ids[i]] = 1;
}

// 2-level scan: per-block inclusive scan of 1024 ints + block sums
__global__ __launch_bounds__(256) void k_scan1(int* __restrict__ cum, int* __restrict__ bsum, int G) {
    __shared__ int ws[4];
    int tid = threadIdx.x;
    int base = blockIdx.x * 1024 + tid * 4;
    int a0 = 0, a1 = 0, a2 = 0, a3 = 0;
    if (base + 0 < G) a0 = cum[base + 0];
    if (base + 1 < G) a1 = cum[base + 1];
    if (base + 2 < G) a2 = cum[base + 2];
    if (base + 3 < G) a3 = cum[base + 3];
    int s = a0 + a1 + a2 + a3;
    int lane = tid & 63;
    int v = s;
#pragma unroll
    for (int off = 1; off < 64; off <<= 1) {
        int u = __shfl_up(v, off, 64);
        if (lane >= off) v += u;
    }
    if (lane == 63) ws[tid >> 6] = v;
    __syncthreads();
    int wof = 0;
    for (int w = 0; w < (tid >> 6); ++w) wof += ws[w];
    int excl = wof + v - s;
    int r0 = excl + a0, r1 = r0 + a1, r2 = r1 + a2, r3 = r2 + a3;
    if (base + 0 < G) cum[base + 0] = r0;
    if (base + 1 < G) cum[base + 1] = r1;
    if (base + 2 < G) cum[base + 2] = r2;
    if (base + 3 < G) cum[base + 3] = r3;
    if (tid == 255) bsum[blockIdx.x] = excl + s;
}

__global__ void k_scan2(int* __restrict__ bsum, int nb) {
    int t = threadIdx.x;  // 64 threads, nb <= 64
    int v = (t < nb) ? bsum[t] : 0;
#pragma unroll
    for (int off = 1; off < 64; off <<= 1) {
        int u = __shfl_up(v, off, 64);
        if (t >= off) v += u;
    }
    if (t < nb) bsum[t] = v;
}

__global__ void k_gid(const int* __restrict__ ids, const int* __restrict__ cum,
                      const int* __restrict__ bsum, int* __restrict__ gid,
                      int* __restrict__ gstart, int* __restrict__ ngr, int n) {
    int i = blockIdx.x * blockDim.x + threadIdx.x;
    if (i >= n) return;
    int v = ids[i];
    int blk = v >> 10;
    int g = cum[v] + (blk ? bsum[blk - 1] : 0) - 1;
    gid[i] = g;
    if (i == 0 || ids[i - 1] != v) gstart[g] = i;
    if (i == n - 1) { gstart[g + 1] = n; *ngr = g + 1; }
}

// E1 = emb @ W1b^T  (f32 out). DMA-pipelined, B in VGPRs.
__global__ __launch_bounds__(256, 3) void k_egemm(
    const float* __restrict__ emb, const unsigned short* __restrict__ W1b,
    float* __restrict__ E1, int G) {
    __shared__ __align__(16) float ebuf[2][4096];
    int tid = threadIdx.x, lane = tid & 63, wid = tid >> 6;
    int p = lane & 15, q = lane >> 4;
    int wr = wid >> 1, wc = wid & 1;
    long long row0 = (long long)blockIdx.x * 256;

    short8 bfr[4][4];
#pragma unroll
    for (int t = 0; t < 4; ++t)
#pragma unroll
        for (int kk = 0; kk < 4; ++kk)
            bfr[t][kk] = *(const short8*)&W1b[(size_t)(wc * 64 + t * 16 + p) * 128 + kk * 32 + q * 8];

    dma_chunk(emb, (char*)&ebuf[0][0], row0, G, wid, lane);
    dma_chunk(emb, (char*)&ebuf[1][0], row0 + 32, G, wid, lane);
    asm volatile("s_waitcnt vmcnt(4)" ::: "memory");
    __builtin_amdgcn_s_barrier();
    __builtin_amdgcn_sched_barrier(0);

    for (int c = 0; c < 8; ++c) {
        const float* xb = &ebuf[c & 1][0];
        int grB = (int)row0 + c * 32;
        f32x4 acc[4];
#pragma unroll
        for (int t = 0; t < 4; ++t) acc[t] = f32x4{0.f, 0.f, 0.f, 0.f};
        short8 afr[4];
        int sw = (p & 7) << 4;
        int lr = wr * 16 + p;
#pragma unroll
        for (int kk = 0; kk < 4; ++kk) {
            int boff = lr * 512 + kk * 128 + q * 32;
            float4 v0 = lds_rd16(xb, boff, sw);
            float4 v1 = lds_rd16(xb, boff + 16, sw);
            short8 a;
            a[0] = (short)f2bf(v0.x); a[1] = (short)f2bf(v0.y);
            a[2] = (short)f2bf(v0.z); a[3] = (short)f2bf(v0.w);
            a[4] = (short)f2bf(v1.x); a[5] = (short)f2bf(v1.y);
            a[6] = (short)f2bf(v1.z); a[7] = (short)f2bf(v1.w);
            afr[kk] = a;
        }
#pragma unroll
        for (int t = 0; t < 4; ++t)
#pragma unroll
            for (int kk = 0; kk < 4; ++kk)
                acc[t] = __builtin_amdgcn_mfma_f32_16x16x32_bf16(afr[kk], bfr[t][kk], acc[t], 0, 0, 0);
#pragma unroll
        for (int t = 0; t < 4; ++t) {
            int colb = wc * 64 + t * 16 + p;
#pragma unroll
            for (int rg = 0; rg < 4; ++rg) {
                int rr = grB + wr * 16 + q * 4 + rg;
                if (rr < G) E1[(size_t)rr * 128 + colb] = acc[t][rg];
            }
        }
        if (c == 7) break;
        __builtin_amdgcn_s_barrier();
        if (c < 6) {
            dma_chunk(emb, (char*)&ebuf[c & 1][0], row0 + (long long)(c + 2) * 32, G, wid, lane);
            asm volatile("s_waitcnt vmcnt(4)" ::: "memory");
        } else {
            asm volatile("s_waitcnt vmcnt(0)" ::: "memory");
        }
        __builtin_amdgcn_s_barrier();
        __builtin_amdgcn_sched_barrier(0);
    }
}

// x_out = x @ W1a^T + E1[gid] + b1 ; fused in-register segmented sums -> segsum
__global__ __launch_bounds__(256, 3) void k_xgemm(
    const float* __restrict__ x, const unsigned short* __restrict__ W1a,
    const int* __restrict__ gid, const float* __restrict__ E1,
    const float* __restrict__ b1, float* __restrict__ out,
    float* __restrict__ segsum, int N) {
    __shared__ __align__(16) float xbuf[2][4096];
    int tid = threadIdx.x, lane = tid & 63, wid = tid >> 6;
    int p = lane & 15, q = lane >> 4;
    int wr = wid >> 1, wc = wid & 1;
    long long row0 = (long long)blockIdx.x * 256;

    short8 bfr[4][4];
#pragma unroll
    for (int t = 0; t < 4; ++t)
#pragma unroll
        for (int kk = 0; kk < 4; ++kk)
            bfr[t][kk] = *(const short8*)&W1a[(size_t)(wc * 64 + t * 16 + p) * 128 + kk * 32 + q * 8];
    float b1v[4];
#pragma unroll
    for (int t = 0; t < 4; ++t) b1v[t] = b1[wc * 64 + t * 16 + p];

    dma_chunk(x, (char*)&xbuf[0][0], row0, N, wid, lane);
    dma_chunk(x, (char*)&xbuf[1][0], row0 + 32, N, wid, lane);
    asm volatile("s_waitcnt vmcnt(4)" ::: "memory");
    __builtin_amdgcn_s_barrier();
    __builtin_amdgcn_sched_barrier(0);

    for (int c = 0; c < 8; ++c) {
        const float* xb = &xbuf[c & 1][0];
        int grB = (int)row0 + c * 32;
        int myrow = grB + wr * 16 + p;
        int g = gid[myrow < N ? myrow : (N - 1)];
        // segment boundary prep (rows = p within this wave's 16-row tile)
        int gpv = __shfl(g, lane > 0 ? lane - 1 : 0);
        int gnx = __shfl(g, lane < 63 ? lane + 1 : 63);
        bool is_start = (p == 0) || (gpv != g);
        bool is_end = (p == 15) || (gnx != g);
        ull smask = __ballot(is_start);
        ull below = smask & (~0ULL >> (63 - lane));
        int startlane = 63 - __builtin_clzll(below);
        bool has_before = (startlane & 15) != 0;
        int pbl = startlane > 0 ? startlane - 1 : 0;

        f32x4 acc[4];
#pragma unroll
        for (int t = 0; t < 4; ++t) acc[t] = f32x4{0.f, 0.f, 0.f, 0.f};
        short8 afr[4];
        int sw = (p & 7) << 4;
        int lr = wr * 16 + p;
#pragma unroll
        for (int kk = 0; kk < 4; ++kk) {
            int boff = lr * 512 + kk * 128 + q * 32;
            float4 v0 = lds_rd16(xb, boff, sw);
            float4 v1 = lds_rd16(xb, boff + 16, sw);
            float v[8] = {v0.x, v0.y, v0.z, v0.w, v1.x, v1.y, v1.z, v1.w};
            short8 a;
#pragma unroll
            for (int j = 0; j < 8; ++j) a[j] = (short)f2bf(v[j]);
            afr[kk] = a;
            if (wc == 0) {  // waves 0,2: segmented inclusive scan over 16 lanes (rows)
#pragma unroll
                for (int j = 0; j < 8; ++j) { float u = __shfl_up(v[j], 1, 16); if (p >= 1) v[j] += u; }
#pragma unroll
                for (int j = 0; j < 8; ++j) { float u = __shfl_up(v[j], 2, 16); if (p >= 2) v[j] += u; }
#pragma unroll
                for (int j = 0; j < 8; ++j) { float u = __shfl_up(v[j], 4, 16); if (p >= 4) v[j] += u; }
#pragma unroll
                for (int j = 0; j < 8; ++j) { float u = __shfl_up(v[j], 8, 16); if (p >= 8) v[j] += u; }
#pragma unroll
                for (int j = 0; j < 8; ++j) {
                    float pb = __shfl(v[j], pbl);
                    if (is_end) {
                        float seg = v[j] - (has_before ? pb : 0.f);
                        atomicAdd(&segsum[(size_t)g * 128 + kk * 32 + q * 8 + j], seg);
                    }
                }
            }
        }
#pragma unroll
        for (int t = 0; t < 4; ++t)
#pragma unroll
            for (int kk = 0; kk < 4; ++kk)
                acc[t] = __builtin_amdgcn_mfma_f32_16x16x32_bf16(afr[kk], bfr[t][kk], acc[t], 0, 0, 0);

        int g4[4];
#pragma unroll
        for (int rg = 0; rg < 4; ++rg) g4[rg] = __shfl(g, q * 4 + rg);
#pragma unroll
        for (int t = 0; t < 4; ++t) {
            int colb = wc * 64 + t * 16 + p;
#pragma unroll
            for (int rg = 0; rg < 4; ++rg) {
                int rr = grB + wr * 16 + q * 4 + rg;
                if (rr < N)
                    out[(size_t)rr * 128 + colb] = acc[t][rg] + E1[(size_t)g4[rg] * 128 + colb] + b1v[t];
            }
        }
        if (c == 7) break;
        __builtin_amdgcn_s_barrier();
        if (c < 6) {
            dma_chunk(x, (char*)&xbuf[c & 1][0], row0 + (long long)(c + 2) * 32, N, wid, lane);
            asm volatile("s_waitcnt vmcnt(4)" ::: "memory");
        } else {
            asm volatile("s_waitcnt vmcnt(0)" ::: "memory");
        }
        __builtin_amdgcn_s_barrier();
        __builtin_amdgcn_sched_barrier(0);
    }
}

// imputed_out = emb @ W2a^T + imp_second @ W2b^T + b2, mean computed in-register
__global__ __launch_bounds__(256, 2) void k_igemm(
    const float* __restrict__ emb, const float* __restrict__ segsum,
    const unsigned short* __restrict__ W2a, const unsigned short* __restrict__ W2b,
    const float* __restrict__ b2, const int* __restrict__ gstart,
    const int* __restrict__ ngr, float* __restrict__ out2, int G) {
    __shared__ __align__(16) float ebuf[2][4096];
    __shared__ __align__(16) float sbuf[2][4096];
    int tid = threadIdx.x, lane = tid & 63, wid = tid >> 6;
    int p = lane & 15, q = lane >> 4;
    int wr = wid >> 1, wc = wid & 1;
    long long row0 = (long long)blockIdx.x * 256;
    int ng = *ngr;

    short8 bfrA[4][4], bfrB[4][4];
#pragma unroll
    for (int t = 0; t < 4; ++t)
#pragma unroll
        for (int kk = 0; kk < 4; ++kk) {
            bfrA[t][kk] = *(const short8*)&W2a[(size_t)(wc * 64 + t * 16 + p) * 128 + kk * 32 + q * 8];
            bfrB[t][kk] = *(const short8*)&W2b[(size_t)(wc * 64 + t * 16 + p) * 128 + kk * 32 + q * 8];
        }
    float b2v[4];
#pragma unroll
    for (int t = 0; t < 4; ++t) b2v[t] = b2[wc * 64 + t * 16 + p];

    dma_chunk(emb, (char*)&ebuf[0][0], row0, G, wid, lane);
    dma_chunk(segsum, (char*)&sbuf[0][0], row0, G, wid, lane);
    dma_chunk(emb, (char*)&ebuf[1][0], row0 + 32, G, wid, lane);
    dma_chunk(segsum, (char*)&sbuf[1][0], row0 + 32, G, wid, lane);
    asm volatile("s_waitcnt vmcnt(8)" ::: "memory");
    __builtin_amdgcn_s_barrier();
    __builtin_amdgcn_sched_barrier(0);

    for (int c = 0; c < 8; ++c) {
        const float* eb = &ebuf[c & 1][0];
        const float* sb = &sbuf[c & 1][0];
        int grB = (int)row0 + c * 32;
        int myrow = grB + wr * 16 + p;
        int grc = myrow < G ? myrow : (G - 1);
        bool written = grc < ng - 1;
        int cnt = 1;
        if (written) cnt = gstart[grc + 1] - gstart[grc];
        float invc = 1.0f / (float)(cnt > 0 ? cnt : 1);

        f32x4 acc[4];
#pragma unroll
        for (int t = 0; t < 4; ++t) acc[t] = f32x4{0.f, 0.f, 0.f, 0.f};
        short8 ae[4], am[4];
        int sw = (p & 7) << 4;
        int lr = wr * 16 + p;
#pragma unroll
        for (int kk = 0; kk < 4; ++kk) {
            int boff = lr * 512 + kk * 128 + q * 32;
            float4 e0 = lds_rd16(eb, boff, sw);
            float4 e1 = lds_rd16(eb, boff + 16, sw);
            float4 s0 = lds_rd16(sb, boff, sw);
            float4 s1 = lds_rd16(sb, boff + 16, sw);
            float ve[8] = {e0.x, e0.y, e0.z, e0.w, e1.x, e1.y, e1.z, e1.w};
            float vs[8] = {s0.x, s0.y, s0.z, s0.w, s1.x, s1.y, s1.z, s1.w};
            short8 a, m;
#pragma unroll
            for (int j = 0; j < 8; ++j) {
                a[j] = (short)f2bf(ve[j]);
                m[j] = (short)f2bf(written ? vs[j] * invc : ve[j]);
            }
            ae[kk] = a; am[kk] = m;
        }
#pragma unroll
        for (int t = 0; t < 4; ++t)
#pragma unroll
            for (int kk = 0; kk < 4; ++kk) {
                acc[t] = __builtin_amdgcn_mfma_f32_16x16x32_bf16(ae[kk], bfrA[t][kk], acc[t], 0, 0, 0);
                acc[t] = __builtin_amdgcn_mfma_f32_16x16x32_bf16(am[kk], bfrB[t][kk], acc[t], 0, 0, 0);
            }
#pragma unroll
        for (int t = 0; t < 4; ++t) {
            int colb = wc * 64 + t * 16 + p;
#pragma unroll
            for (int rg = 0; rg < 4; ++rg) {
                int rr = grB + wr * 16 + q * 4 + rg;
                if (rr < G) out2[(size_t)rr * 128 + colb] = acc[t][rg] + b2v[t];
            }
        }
        if (c == 7) break;
        __builtin_amdgcn_s_barrier();
        if (c < 6) {
            dma_chunk(emb, (char*)&ebuf[c & 1][0], row0 + (long long)(c + 2) * 32, G, wid, lane);
            dma_chunk(segsum, (char*)&sbuf[c & 1][0], row0 + (long long)(c + 2) * 32, G, wid, lane);
            asm volatile("s_waitcnt vmcnt(8)" ::: "memory");
        } else {
            asm volatile("s_waitcnt vmcnt(0)" ::: "memory");
        }
        __builtin_amdgcn_s_barrier();
        __builtin_amdgcn_sched_barrier(0);
    }
}

extern "C" void kernel_launch(void* const* d_in, const int* in_sizes, int n_in,
                              void* d_out, int out_size, void* d_ws, size_t ws_size,
                              hipStream_t stream) {
    const float* x   = (const float*)d_in[0];
    const float* emb = (const float*)d_in[1];
    const float* W1  = (const float*)d_in[2];
    const float* b1  = (const float*)d_in[3];
    const float* W2  = (const float*)d_in[4];
    const float* b2  = (const float*)d_in[5];
    const int*   ids = (const int*)d_in[6];
    const int H = 128;
    const int N = in_sizes[6];
    const int G = in_sizes[1] / H;

    float* out  = (float*)d_out;
    float* out2 = out + (size_t)N * H;
    float* E1   = out2;  // E1 scratch lives in imputed_out region (overwritten by k_igemm last)

    char* ws = (char*)d_ws;
    size_t off = 0;
    float* segsum = (float*)(ws + off); off += (size_t)G * H * 4;
    int*   cum    = (int*)(ws + off);   off += (size_t)G * 4;
    size_t zbytes = off;                              // contiguous zero region: segsum + cum
    off = (off + 255) & ~(size_t)255;
    int* bsum   = (int*)(ws + off); off += 64 * 4;          off = (off + 255) & ~(size_t)255;
    int* gid    = (int*)(ws + off); off += (size_t)N * 4;   off = (off + 255) & ~(size_t)255;
    int* gstart = (int*)(ws + off); off += (size_t)(G + 1) * 4; off = (off + 255) & ~(size_t)255;
    int* ngr    = (int*)(ws + off); off += 256;
    unsigned short* W1a = (unsigned short*)(ws + off); off += (size_t)H * H * 2;
    unsigned short* W1b = (unsigned short*)(ws + off); off += (size_t)H * H * 2;
    unsigned short* W2a = (unsigned short*)(ws + off); off += (size_t)H * H * 2;
    unsigned short* W2b = (unsigned short*)(ws + off); off += (size_t)H * H * 2;

    int n16 = (int)(zbytes / 16);
    int nb = (G + 1023) >> 10;
    k_zero<<<(n16 + 255) / 256, 256, 0, stream>>>((uint4*)ws, n16);
    k_convw<<<H, 256, 0, stream>>>(W1, W2, W1a, W1b, W2a, W2b);
    k_mark<<<(N + 255) / 256, 256, 0, stream>>>(ids, cum, N);
    k_scan1<<<nb, 256, 0, stream>>>(cum, bsum, G);
    k_scan2<<<1, 64, 0, stream>>>(bsum, nb);
    k_gid<<<(N + 255) / 256, 256, 0, stream>>>(ids, cum, bsum, gid, gstart, ngr, N);
    k_egemm<<<(G + 255) / 256, 256, 0, stream>>>(emb, W1b, E1, G);
    k_xgemm<<<(N + 255) / 256, 256, 0, stream>>>(x, W1a, gid, E1, b1, out, segsum, N);
    k_igemm<<<(G + 255) / 256, 256, 0, stream>>>(emb, segsum, W2a, W2b, b2, gstart, ngr, out2, G);
}